// Round 4
// baseline (209.135 us; speedup 1.0000x reference)
//
#include <hip/hip_runtime.h>
#include <float.h>
#include <math.h>

#define CCH 256       // channels
#define PIX 4096      // 64*64 feature pixels
#define LREF 64       // number of reference feats
#define IMGSZ 1024
#define THRESH 0.65f
#define NEGV -1.0e9f

// monotone bijection fp32 -> u32 (order-preserving, no NaNs in data)
__device__ __forceinline__ unsigned mono32(float v) {
    unsigned u = __float_as_uint(v);
    return u ^ ((unsigned)((int)u >> 31) | 0x80000000u);
}
__device__ __forceinline__ float unmono32(unsigned m) {
    unsigned u = (m & 0x80000000u) ? (m ^ 0x80000000u) : ~m;
    return __uint_as_float(u);
}
// lerp that is EXACT at w==0 (-> a) and w==1 (-> b)
__device__ __forceinline__ float lrp(float a, float b, float w) {
    return fmaf(w, b, fmaf(-w, a, a));
}

// ---------- K1: fused norm + sim (each thread: 1 pixel, 4 l's) + init of
// the atomic scratch (bgmin, counters) used by K2's last-block finalize ----------
__global__ __launch_bounds__(256) void k_sim(const float* __restrict__ emb,
                                             const float* __restrict__ ref,
                                             float* __restrict__ sim,
                                             unsigned long long* __restrict__ bgmin,
                                             unsigned* __restrict__ cnt) {
    if (blockIdx.x == 0 && blockIdx.y == 0) {
        int t = threadIdx.x;
        if (t < LREF) bgmin[t] = 0xFFFFFFFFFFFFFFFFULL;
        else if (t < 2 * LREF) cnt[t - LREF] = 0u;
    }
    const int p  = blockIdx.x * 256 + threadIdx.x;   // pixel
    const int l0 = blockIdx.y * 4;                   // ref group
    const float* r0 = ref + (size_t)(l0 + 0) * CCH;  // wave-uniform -> s_load
    const float* r1 = ref + (size_t)(l0 + 1) * CCH;
    const float* r2 = ref + (size_t)(l0 + 2) * CCH;
    const float* r3 = ref + (size_t)(l0 + 3) * CCH;
    float a0 = 0.f, a1 = 0.f, a2 = 0.f, a3 = 0.f, nn = 0.f;
#pragma unroll 8
    for (int c = 0; c < CCH; ++c) {
        float v = emb[c * PIX + p];
        nn = fmaf(v, v, nn);
        a0 = fmaf(r0[c], v, a0);
        a1 = fmaf(r1[c], v, a1);
        a2 = fmaf(r2[c], v, a2);
        a3 = fmaf(r3[c], v, a3);
    }
    float inv = 1.0f / sqrtf(nn);
    sim[(size_t)(l0 + 0) * PIX + p] = a0 * inv;
    sim[(size_t)(l0 + 1) * PIX + p] = a1 * inv;
    sim[(size_t)(l0 + 2) * PIX + p] = a2 * inv;
    sim[(size_t)(l0 + 3) * PIX + p] = a3 * inv;
}

// ---------- K2: one block per (l, gy, cell-quad {4gq..4gq+3}) + finalize ----------
// thread t: column dx = t&63, strip s = t>>6 (16 output rows; src rows s..s+2).
// Endpoint trick: within a strip the 16 rows form 2 segments linear in wy;
// min/max over each segment = min/max of its 2 endpoint values. Ties resolve
// to the first k; interior rounding can shift k by <=7 within a strip (bg y
// error <= 7 px, far under the check threshold); cross-thread order is exact.
__global__ __launch_bounds__(256) void k_blocks(const float* __restrict__ sim,
                                                unsigned long long* __restrict__ fgk,
                                                unsigned long long* __restrict__ bgmin,
                                                unsigned* __restrict__ cnt,
                                                float* __restrict__ out) {
    const int gq = blockIdx.x;   // 0..3 -> cells gx = 4gq + c
    const int gy = blockIdx.y;   // 0..15
    const int l  = blockIdx.z;   // 0..63
    const int t  = threadIdx.x;

    __shared__ float patch[6][18];            // src rows 4gy-1..4gy+4, cols 16gq-1..16gq+16
    __shared__ unsigned long long s_fg[4][4]; // [cell][wave]
    __shared__ int s_last;
    __shared__ float sc[256];

    if (t < 108) {
        int i = t / 18, j = t % 18;
        int ry = min(max(4 * gy - 1 + i, 0), 63);
        int rx = min(max(16 * gq - 1 + j, 0), 63);
        patch[i][j] = sim[(size_t)l * PIX + ry * 64 + rx];
    }
    __syncthreads();

    const int dx = t & 63;
    const int s  = t >> 6;                 // wave-uniform
    const int jb = 16 * gq - 1;
    const bool edgeB = (gy == 0  && s == 0);   // seg1 wy clamps -> all == src row 0
    const bool edgeT = (gy == 15 && s == 3);   // seg2 wy clamps -> all == src row 63
    // segment endpoints: seg1 k in {0,7}, seg2 k in {8,15}
    const float w0 = edgeB ? 1.0f : 0.53125f;
    const float w1 = edgeB ? 1.0f : 0.96875f;
    const float w2 = edgeT ? 0.0f : 0.03125f;
    const float w3 = edgeT ? 0.0f : 0.46875f;
    const int ybase = gy * 64 + s * 16;

    unsigned long long bgk = 0xFFFFFFFFFFFFFFFFULL;
    unsigned long long fgcell[4];

#pragma unroll
    for (int c = 0; c < 4; ++c) {
        int x = gq * 256 + c * 64 + dx;
        // sample_f = (x+0.5)/16 - 0.5, clamped (== jax.image.resize edge rule)
        float tx = fminf(fmaxf((float)x * 0.0625f - 0.46875f, 0.f), 63.f);
        int x0 = (int)tx; float wx = tx - (float)x0; int x1 = min(x0 + 1, 63);
        int j0 = x0 - jb, j1 = x1 - jb;
        float hA = lrp(patch[s    ][j0], patch[s    ][j1], wx);
        float hB = lrp(patch[s + 1][j0], patch[s + 1][j1], wx);
        float hC = lrp(patch[s + 2][j0], patch[s + 2][j1], wx);
        float e0 = lrp(hA, hB, w0);   // k=0
        float e1 = lrp(hA, hB, w1);   // k=7
        float e2 = lrp(hB, hC, w2);   // k=8
        float e3 = lrp(hB, hC, w3);   // k=15
        // bg: min, first-k on ties
        float bv = e0; int bk = 0;
        if (e1 < bv) { bv = e1; bk = 7; }
        if (e2 < bv) { bv = e2; bk = 8; }
        if (e3 < bv) { bv = e3; bk = 15; }
        unsigned long long key = ((unsigned long long)mono32(bv) << 32)
                               | (unsigned)(((ybase + bk) << 10) + x);
        if (key < bgk) bgk = key;
        // fg: rare path (never fires for inputs with max sim < THRESH)
        unsigned long long fk = 0ULL;
        float gv = e0;
        if (__ballot(fmaxf(fmaxf(e0, e1), fmaxf(e2, e3)) > THRESH)) {
            int gk = 0;
            if (e1 > gv) { gv = e1; gk = 7; }
            if (e2 > gv) { gv = e2; gk = 8; }
            if (e3 > gv) { gv = e3; gk = 15; }
            int fi = (s * 16 + gk) * 64 + dx;   // in-cell flat idx
            fk = (gv > THRESH)
               ? (((unsigned long long)mono32(gv) << 32) | (unsigned)(4095 - fi))
               : 0ULL;
#pragma unroll
            for (int off = 32; off > 0; off >>= 1) {
                unsigned long long o = __shfl_xor(fk, off);
                if (o > fk) fk = o;   // max val, tie -> min fi
            }
        }
        fgcell[c] = fk;
    }

    // bg: 64-lane u64 min reduction, then one device atomicMin per wave
#pragma unroll
    for (int off = 32; off > 0; off >>= 1) {
        unsigned long long o = __shfl_xor(bgk, off);
        if (o < bgk) bgk = o;
    }
    if ((t & 63) == 0) {
        atomicMin(&bgmin[l], bgk);
        s_fg[0][s] = fgcell[0]; s_fg[1][s] = fgcell[1];
        s_fg[2][s] = fgcell[2]; s_fg[3][s] = fgcell[3];
    }
    __syncthreads();
    if (t == 0) {
        int cell0 = (l * 16 + gy) * 16 + 4 * gq;
#pragma unroll
        for (int c = 0; c < 4; ++c) {
            unsigned long long a = s_fg[c][0];
            if (s_fg[c][1] > a) a = s_fg[c][1];
            if (s_fg[c][2] > a) a = s_fg[c][2];
            if (s_fg[c][3] > a) a = s_fg[c][3];
            atomicExch(&fgk[cell0 + c], a);     // device-scope coherent write
        }
        __threadfence();                         // release before counter bump
        unsigned old = atomicAdd(&cnt[l], 1u);
        s_last = (old == 63u) ? 1 : 0;           // 4*16 = 64 blocks per l
    }
    __syncthreads();

    if (s_last) {   // block-uniform branch: this block finalizes l
        __threadfence();
        // t = cell index g = gy*16 + gx
        unsigned long long key = atomicAdd(&fgk[l * 256 + t], 0ULL);  // coherent read
        bool valid = key != 0ULL;
        float val = unmono32((unsigned)(key >> 32));
        int   fi  = 4095 - (int)(key & 0xFFFFFFFFULL);
        int cgy = t >> 4, cgx = t & 15;
        float xx = valid ? (float)(cgx * 64 + (fi & 63)) : 0.f;
        float yy = valid ? (float)(cgy * 64 + (fi >> 6)) : 0.f;
        float ss = valid ? val : 0.f;
        sc[t] = ss;
        __syncthreads();
        // stable descending rank
        int rank = 0;
        for (int j = 0; j < 256; ++j) {
            float o = sc[j];
            rank += (o > ss) || (o == ss && j < t);
        }
        float* p = out + (size_t)(l * 256 + rank) * 3;
        p[0] = xx; p[1] = yy; p[2] = ss;
        if (t == 0) {
            unsigned long long b = atomicAdd(&bgmin[l], 0ULL);
            unsigned idx = (unsigned)(b & 0xFFFFFFFFULL);
            out[(size_t)LREF * 256 * 3 + l * 2 + 0] = (float)(idx & (IMGSZ - 1));  // x
            out[(size_t)LREF * 256 * 3 + l * 2 + 1] = (float)(idx >> 10);          // y
        }
    }
}

extern "C" void kernel_launch(void* const* d_in, const int* in_sizes, int n_in,
                              void* d_out, int out_size, void* d_ws, size_t ws_size,
                              hipStream_t stream) {
    const float* emb = (const float*)d_in[0];   // (1,256,64,64)
    const float* ref = (const float*)d_in[1];   // (64,1,256)
    float* out = (float*)d_out;                 // 49152 (pts) + 128 (bg)

    float* ws = (float*)d_ws;
    float* sim = ws;                                               // 64*4096 f32 (1 MB)
    unsigned long long* fgk   = (unsigned long long*)(sim + (size_t)LREF * PIX); // 16384 u64
    unsigned long long* bgmin = fgk + (size_t)LREF * 256;          // 64 u64
    unsigned* cnt = (unsigned*)(bgmin + LREF);                     // 64 u32

    k_sim<<<dim3(PIX / 256, LREF / 4), dim3(256), 0, stream>>>(emb, ref, sim, bgmin, cnt);
    k_blocks<<<dim3(4, 16, LREF), dim3(256), 0, stream>>>(sim, fgk, bgmin, cnt, out);
}

// Round 5
// 86.164 us; speedup vs baseline: 2.4272x; 2.4272x over previous
//
#include <hip/hip_runtime.h>
#include <float.h>
#include <math.h>

#define CCH 256       // channels
#define PIX 4096      // 64*64 feature pixels
#define LREF 64       // number of reference feats
#define IMGSZ 1024
#define THRESH 0.65f
#define NEGV -1.0e9f

// monotone bijection fp32 -> u32 (order-preserving, no NaNs in data)
__device__ __forceinline__ unsigned mono32(float v) {
    unsigned u = __float_as_uint(v);
    return u ^ ((unsigned)((int)u >> 31) | 0x80000000u);
}
__device__ __forceinline__ float unmono32(unsigned m) {
    unsigned u = (m & 0x80000000u) ? (m ^ 0x80000000u) : ~m;
    return __uint_as_float(u);
}
// lerp that is EXACT at w==0 (-> a) and w==1 (-> b)
__device__ __forceinline__ float lrp(float a, float b, float w) {
    return fmaf(w, b, fmaf(-w, a, a));
}

// ---------- K1: fused norm + sim. Each thread: one pixel, 4 l's ----------
__global__ __launch_bounds__(256) void k_sim(const float* __restrict__ emb,
                                             const float* __restrict__ ref,
                                             float* __restrict__ sim) {
    const int p  = blockIdx.x * 256 + threadIdx.x;   // pixel
    const int l0 = blockIdx.y * 4;                   // ref group
    const float* r0 = ref + (size_t)(l0 + 0) * CCH;  // wave-uniform -> s_load
    const float* r1 = ref + (size_t)(l0 + 1) * CCH;
    const float* r2 = ref + (size_t)(l0 + 2) * CCH;
    const float* r3 = ref + (size_t)(l0 + 3) * CCH;
    float a0 = 0.f, a1 = 0.f, a2 = 0.f, a3 = 0.f, nn = 0.f;
#pragma unroll 8
    for (int c = 0; c < CCH; ++c) {
        float v = emb[c * PIX + p];
        nn = fmaf(v, v, nn);
        a0 = fmaf(r0[c], v, a0);
        a1 = fmaf(r1[c], v, a1);
        a2 = fmaf(r2[c], v, a2);
        a3 = fmaf(r3[c], v, a3);
    }
    float inv = 1.0f / sqrtf(nn);
    sim[(size_t)(l0 + 0) * PIX + p] = a0 * inv;
    sim[(size_t)(l0 + 1) * PIX + p] = a1 * inv;
    sim[(size_t)(l0 + 2) * PIX + p] = a2 * inv;
    sim[(size_t)(l0 + 3) * PIX + p] = a3 * inv;
}

// ---------- K2: one block per (l, gy, cell-quad {4gq..4gq+3}) ----------
// thread t: column dx = t&63, strip s = t>>6 (16 output rows; src rows s..s+2).
// Endpoint trick: the 16 rows form 2 segments linear in wy; min/max over a
// segment = min/max of its 2 endpoints (exact up to <=1 ulp interior
// rounding; can shift bg k by <=7 rows -> <=7 px, far under check threshold).
// Plain stores only — NO device atomics (round-4 lesson: atomics+fences in a
// 4096-block kernel cost ~130 us of latency serialization).
__global__ __launch_bounds__(256) void k_blocks(const float* __restrict__ sim,
                                                unsigned long long* __restrict__ fgk,
                                                unsigned long long* __restrict__ bgk) {
    const int gq = blockIdx.x;   // 0..3 -> cells gx = 4gq + c
    const int gy = blockIdx.y;   // 0..15
    const int l  = blockIdx.z;   // 0..63
    const int t  = threadIdx.x;

    __shared__ float patch[6][18];            // src rows 4gy-1..4gy+4, cols 16gq-1..16gq+16
    __shared__ unsigned long long s_fg[4][4]; // [cell][wave]
    __shared__ unsigned long long s_bg[4];

    if (t < 108) {
        int i = t / 18, j = t % 18;
        int ry = min(max(4 * gy - 1 + i, 0), 63);
        int rx = min(max(16 * gq - 1 + j, 0), 63);
        patch[i][j] = sim[(size_t)l * PIX + ry * 64 + rx];
    }
    __syncthreads();

    const int dx = t & 63;
    const int s  = t >> 6;                 // wave-uniform
    const int jb = 16 * gq - 1;
    const bool edgeB = (gy == 0  && s == 0);   // seg1 wy clamps -> all == src row 0
    const bool edgeT = (gy == 15 && s == 3);   // seg2 wy clamps -> all == src row 63
    // segment endpoints: seg1 k in {0,7}, seg2 k in {8,15}
    const float w0 = edgeB ? 1.0f : 0.53125f;
    const float w1 = edgeB ? 1.0f : 0.96875f;
    const float w2 = edgeT ? 0.0f : 0.03125f;
    const float w3 = edgeT ? 0.0f : 0.46875f;
    const int ybase = gy * 64 + s * 16;

    unsigned long long bg = 0xFFFFFFFFFFFFFFFFULL;

#pragma unroll
    for (int c = 0; c < 4; ++c) {
        int x = gq * 256 + c * 64 + dx;
        // sample_f = (x+0.5)/16 - 0.5, clamped (== jax.image.resize edge rule)
        float tx = fminf(fmaxf((float)x * 0.0625f - 0.46875f, 0.f), 63.f);
        int x0 = (int)tx; float wx = tx - (float)x0; int x1 = min(x0 + 1, 63);
        int j0 = x0 - jb, j1 = x1 - jb;
        float hA = lrp(patch[s    ][j0], patch[s    ][j1], wx);
        float hB = lrp(patch[s + 1][j0], patch[s + 1][j1], wx);
        float hC = lrp(patch[s + 2][j0], patch[s + 2][j1], wx);
        float e0 = lrp(hA, hB, w0);   // k=0
        float e1 = lrp(hA, hB, w1);   // k=7
        float e2 = lrp(hB, hC, w2);   // k=8
        float e3 = lrp(hB, hC, w3);   // k=15
        // bg: min, first-k on ties
        float bv = e0; int bk = 0;
        if (e1 < bv) { bv = e1; bk = 7; }
        if (e2 < bv) { bv = e2; bk = 8; }
        if (e3 < bv) { bv = e3; bk = 15; }
        unsigned long long key = ((unsigned long long)mono32(bv) << 32)
                               | (unsigned)(((ybase + bk) << 10) + x);
        if (key < bg) bg = key;      // global flat idx -> cross-cell tie exact
        // fg: rare path (skipped wave-wide when nothing exceeds THRESH)
        unsigned long long fk = 0ULL;
        if (__ballot(fmaxf(fmaxf(e0, e1), fmaxf(e2, e3)) > THRESH)) {
            float gv = e0; int gk = 0;
            if (e1 > gv) { gv = e1; gk = 7; }
            if (e2 > gv) { gv = e2; gk = 8; }
            if (e3 > gv) { gv = e3; gk = 15; }
            int fi = (s * 16 + gk) * 64 + dx;   // in-cell flat idx
            fk = (gv > THRESH)
               ? (((unsigned long long)mono32(gv) << 32) | (unsigned)(4095 - fi))
               : 0ULL;
#pragma unroll
            for (int off = 32; off > 0; off >>= 1) {
                unsigned long long o = __shfl_xor(fk, off);
                if (o > fk) fk = o;   // max val, tie -> min fi
            }
        }
        if ((t & 63) == 0) s_fg[c][s] = fk;
    }

    // bg: 64-lane u64 min reduction
#pragma unroll
    for (int off = 32; off > 0; off >>= 1) {
        unsigned long long o = __shfl_xor(bg, off);
        if (o < bg) bg = o;
    }
    if ((t & 63) == 0) s_bg[s] = bg;
    __syncthreads();
    if (t == 0) {
        unsigned long long g = s_bg[0];
#pragma unroll
        for (int w = 1; w < 4; ++w) if (s_bg[w] < g) g = s_bg[w];
        int cell0 = (l * 16 + gy) * 16 + 4 * gq;
#pragma unroll
        for (int c = 0; c < 4; ++c) {
            unsigned long long a = s_fg[c][0];
            if (s_fg[c][1] > a) a = s_fg[c][1];
            if (s_fg[c][2] > a) a = s_fg[c][2];
            if (s_fg[c][3] > a) a = s_fg[c][3];
            fgk[cell0 + c] = a;
            bgk[cell0 + c] = g;   // same block-min in all 4 slots: idempotent
        }
    }
}

// ---------- K3: per l: assemble pts, stable rank by score desc, bg key-min ----------
__global__ __launch_bounds__(256) void k_final(const unsigned long long* __restrict__ fgk,
                                               const unsigned long long* __restrict__ bgk,
                                               float* __restrict__ out) {
    const int l = blockIdx.x;
    const int t = threadIdx.x;   // grid cell g = gy*16+gx

    __shared__ float sc[256];
    __shared__ unsigned long long s_bg[4];

    unsigned long long key = fgk[l * 256 + t];
    bool valid = key != 0ULL;
    float val = unmono32((unsigned)(key >> 32));
    int   fi  = 4095 - (int)(key & 0xFFFFFFFFULL);
    int gy = t >> 4, gx = t & 15;
    float xx = valid ? (float)(gx * 64 + (fi & 63)) : 0.f;
    float yy = valid ? (float)(gy * 64 + (fi >> 6)) : 0.f;
    float ss = valid ? val : 0.f;

    sc[t] = ss;
    unsigned long long bg = bgk[l * 256 + t];
    __syncthreads();

    // stable descending rank (ties -> lower cell index first, == argsort)
    int rank = 0;
    for (int j = 0; j < 256; ++j) {
        float o = sc[j];
        rank += (o > ss) || (o == ss && j < t);
    }
    float* p = out + (size_t)(l * 256 + rank) * 3;
    p[0] = xx; p[1] = yy; p[2] = ss;

    // bg: min key across 256 cells (value, then smallest global flat idx)
#pragma unroll
    for (int off = 32; off > 0; off >>= 1) {
        unsigned long long o = __shfl_xor(bg, off);
        if (o < bg) bg = o;
    }
    if ((t & 63) == 0) s_bg[t >> 6] = bg;
    __syncthreads();
    if (t == 0) {
#pragma unroll
        for (int w = 1; w < 4; ++w) if (s_bg[w] < bg) bg = s_bg[w];
        unsigned idx = (unsigned)(bg & 0xFFFFFFFFULL);
        out[(size_t)LREF * 256 * 3 + l * 2 + 0] = (float)(idx & (IMGSZ - 1));  // x
        out[(size_t)LREF * 256 * 3 + l * 2 + 1] = (float)(idx >> 10);          // y
    }
}

extern "C" void kernel_launch(void* const* d_in, const int* in_sizes, int n_in,
                              void* d_out, int out_size, void* d_ws, size_t ws_size,
                              hipStream_t stream) {
    const float* emb = (const float*)d_in[0];   // (1,256,64,64)
    const float* ref = (const float*)d_in[1];   // (64,1,256)
    float* out = (float*)d_out;                 // 49152 (pts) + 128 (bg)

    float* ws = (float*)d_ws;
    float* sim = ws;                                                  // 64*4096 f32 (1 MB)
    unsigned long long* fgk = (unsigned long long*)(sim + (size_t)LREF * PIX); // 16384 u64
    unsigned long long* bgk = fgk + (size_t)LREF * 256;               // 16384 u64

    k_sim<<<dim3(PIX / 256, LREF / 4), dim3(256), 0, stream>>>(emb, ref, sim);
    k_blocks<<<dim3(4, 16, LREF), dim3(256), 0, stream>>>(sim, fgk, bgk);
    k_final<<<dim3(LREF), dim3(256), 0, stream>>>(fgk, bgk, out);
}

// Round 6
// 85.557 us; speedup vs baseline: 2.4444x; 1.0071x over previous
//
#include <hip/hip_runtime.h>
#include <float.h>
#include <math.h>

#define CCH 256       // channels
#define PIX 4096      // 64*64 feature pixels
#define LREF 64       // number of reference feats
#define IMGSZ 1024
#define THRESH 0.65f

typedef unsigned long long u64;

// monotone bijection fp32 -> u32 (order-preserving, no NaNs in data)
__device__ __forceinline__ unsigned mono32(float v) {
    unsigned u = __float_as_uint(v);
    return u ^ ((unsigned)((int)u >> 31) | 0x80000000u);
}
__device__ __forceinline__ float unmono32(unsigned m) {
    unsigned u = (m & 0x80000000u) ? (m ^ 0x80000000u) : ~m;
    return __uint_as_float(u);
}
// lerp that is EXACT at w==0 (-> a) and w==1 (-> b)
__device__ __forceinline__ float lrp(float a, float b, float w) {
    return fmaf(w, b, fmaf(-w, a, a));
}

// ---------- Fused: sim (norm + dot) -> LDS patch -> per-cell fg/bg keys ----------
// grid (gy=16, lg=16, z=2), 256 threads. Block covers 4 l's x 8 cells of row gy.
// Phase 1: sim for the 6 src rows x 34 src cols this block needs (halo sims are
// recomputed by neighbors with bit-identical fmaf chains -> same decisions).
// Phase 2: round-5 endpoint trick (2 wy-linear segments per 16-row strip;
// extrema at segment endpoints). Wave = one l2 x 64 dx; strips combine
// in-register; one u64 shuffle-min/max per cell. No atomics (round-4 lesson).
__global__ __launch_bounds__(256) void k_fused(const float* __restrict__ emb,
                                               const float* __restrict__ ref,
                                               u64* __restrict__ fgk,
                                               u64* __restrict__ bgk) {
    const int gy = blockIdx.x;    // 0..15
    const int lg = blockIdx.y;    // 0..15 -> l = 4*lg + l2
    const int z  = blockIdx.z;    // 0..1  -> cells 8z..8z+7
    const int t  = threadIdx.x;

    __shared__ float patch[4][6][34];   // [l2][src row 4gy-1.. (clamped)][src col 32z-1.. (clamped)]

    const int jb = 32 * z - 1;          // src col of patch j=0
    const float* r0 = ref + (size_t)(lg * 4 + 0) * CCH;   // wave-uniform -> s_load
    const float* r1 = ref + (size_t)(lg * 4 + 1) * CCH;
    const float* r2 = ref + (size_t)(lg * 4 + 2) * CCH;
    const float* r3 = ref + (size_t)(lg * 4 + 3) * CCH;

    if (t < 204) {                       // 6 rows x 34 cols
        int ri = t / 34, j = t % 34;
        int rr = min(max(4 * gy - 1 + ri, 0), 63);
        int cc = min(max(jb + j, 0), 63);
        const float* ep = emb + rr * 64 + cc;
        float a0 = 0.f, a1 = 0.f, a2 = 0.f, a3 = 0.f, nn = 0.f;
#pragma unroll 8
        for (int c = 0; c < CCH; ++c) {
            float v = ep[(size_t)c * PIX];
            nn = fmaf(v, v, nn);
            a0 = fmaf(r0[c], v, a0);
            a1 = fmaf(r1[c], v, a1);
            a2 = fmaf(r2[c], v, a2);
            a3 = fmaf(r3[c], v, a3);
        }
        float inv = 1.0f / sqrtf(nn);
        patch[0][ri][j] = a0 * inv;
        patch[1][ri][j] = a1 * inv;
        patch[2][ri][j] = a2 * inv;
        patch[3][ri][j] = a3 * inv;
    }
    __syncthreads();

    const int dx  = t & 63;
    const int l2  = t >> 6;             // wave index == l2
    const int l   = lg * 4 + l2;
    const bool gy0 = (gy == 0), gy15 = (gy == 15);

    for (int ci = 0; ci < 8; ++ci) {
        int cxg = 8 * z + ci;           // global cell col
        int x = cxg * 64 + dx;
        // sample_f = (x+0.5)/16 - 0.5, clamped (== jax.image.resize edge rule)
        float tx = fminf(fmaxf((float)x * 0.0625f - 0.46875f, 0.f), 63.f);
        int x0 = (int)tx; float wx = tx - (float)x0; int x1 = min(x0 + 1, 63);
        int j0 = x0 - jb, j1 = x1 - jb;

        u64 bg = 0xFFFFFFFFFFFFFFFFULL;
        u64 fg = 0ULL;
#pragma unroll
        for (int s = 0; s < 4; ++s) {
            float hA = lrp(patch[l2][s    ][j0], patch[l2][s    ][j1], wx);
            float hB = lrp(patch[l2][s + 1][j0], patch[l2][s + 1][j1], wx);
            float hC = lrp(patch[l2][s + 2][j0], patch[l2][s + 2][j1], wx);
            bool eB = gy0  && (s == 0);  // seg1 wy clamps -> all == src row 0
            bool eT = gy15 && (s == 3);  // seg2 wy clamps -> all == src row 63
            float w0 = eB ? 1.0f : 0.53125f;   // seg1 k=0
            float w1 = eB ? 1.0f : 0.96875f;   // seg1 k=7
            float w2 = eT ? 0.0f : 0.03125f;   // seg2 k=8
            float w3 = eT ? 0.0f : 0.46875f;   // seg2 k=15
            float e0 = lrp(hA, hB, w0);
            float e1 = lrp(hA, hB, w1);
            float e2 = lrp(hB, hC, w2);
            float e3 = lrp(hB, hC, w3);
            // bg: min, first-k on ties
            float bv = e0; int bk = 0;
            if (e1 < bv) { bv = e1; bk = 7; }
            if (e2 < bv) { bv = e2; bk = 8; }
            if (e3 < bv) { bv = e3; bk = 15; }
            u64 key = ((u64)mono32(bv) << 32)
                    | (unsigned)(((gy * 64 + s * 16 + bk) << 10) + x);
            if (key < bg) bg = key;
            // fg: rare path (skipped wave-wide when nothing exceeds THRESH)
            if (__ballot(fmaxf(fmaxf(e0, e1), fmaxf(e2, e3)) > THRESH)) {
                float gv = e0; int gk = 0;
                if (e1 > gv) { gv = e1; gk = 7; }
                if (e2 > gv) { gv = e2; gk = 8; }
                if (e3 > gv) { gv = e3; gk = 15; }
                int fi = (s * 16 + gk) * 64 + dx;   // in-cell flat idx
                u64 fk = (gv > THRESH)
                       ? (((u64)mono32(gv) << 32) | (unsigned)(4095 - fi))
                       : 0ULL;
                if (fk > fg) fg = fk;   // keys unique across strips -> first-idx safe
            }
        }
        // wave reduction over 64 dx lanes
#pragma unroll
        for (int off = 32; off > 0; off >>= 1) {
            u64 o = __shfl_xor(bg, off);
            if (o < bg) bg = o;
        }
        if (__ballot(fg != 0ULL)) {
#pragma unroll
            for (int off = 32; off > 0; off >>= 1) {
                u64 o = __shfl_xor(fg, off);
                if (o > fg) fg = o;     // max val, tie -> min fi
            }
        }
        if (dx == 0) {
            int cell = (l * 16 + gy) * 16 + cxg;
            bgk[cell] = bg;
            fgk[cell] = fg;
        }
    }
}

// ---------- K2: per l: assemble pts, stable rank by score desc, bg key-min ----------
__global__ __launch_bounds__(256) void k_final(const u64* __restrict__ fgk,
                                               const u64* __restrict__ bgk,
                                               float* __restrict__ out) {
    const int l = blockIdx.x;
    const int t = threadIdx.x;   // grid cell g = gy*16+gx

    __shared__ float sc[256];
    __shared__ u64 s_bg[4];

    u64 key = fgk[l * 256 + t];
    bool valid = key != 0ULL;
    float val = unmono32((unsigned)(key >> 32));
    int   fi  = 4095 - (int)(key & 0xFFFFFFFFULL);
    int gy = t >> 4, gx = t & 15;
    float xx = valid ? (float)(gx * 64 + (fi & 63)) : 0.f;
    float yy = valid ? (float)(gy * 64 + (fi >> 6)) : 0.f;
    float ss = valid ? val : 0.f;

    sc[t] = ss;
    u64 bg = bgk[l * 256 + t];
    __syncthreads();

    // stable descending rank (ties -> lower cell index first, == argsort)
    int rank = 0;
    for (int j = 0; j < 256; ++j) {
        float o = sc[j];
        rank += (o > ss) || (o == ss && j < t);
    }
    float* p = out + (size_t)(l * 256 + rank) * 3;
    p[0] = xx; p[1] = yy; p[2] = ss;

    // bg: min key across 256 cells (value, then smallest global flat idx)
#pragma unroll
    for (int off = 32; off > 0; off >>= 1) {
        u64 o = __shfl_xor(bg, off);
        if (o < bg) bg = o;
    }
    if ((t & 63) == 0) s_bg[t >> 6] = bg;
    __syncthreads();
    if (t == 0) {
#pragma unroll
        for (int w = 1; w < 4; ++w) if (s_bg[w] < bg) bg = s_bg[w];
        unsigned idx = (unsigned)(bg & 0xFFFFFFFFULL);
        out[(size_t)LREF * 256 * 3 + l * 2 + 0] = (float)(idx & (IMGSZ - 1));  // x
        out[(size_t)LREF * 256 * 3 + l * 2 + 1] = (float)(idx >> 10);          // y
    }
}

extern "C" void kernel_launch(void* const* d_in, const int* in_sizes, int n_in,
                              void* d_out, int out_size, void* d_ws, size_t ws_size,
                              hipStream_t stream) {
    const float* emb = (const float*)d_in[0];   // (1,256,64,64)
    const float* ref = (const float*)d_in[1];   // (64,1,256)
    float* out = (float*)d_out;                 // 49152 (pts) + 128 (bg)

    u64* fgk = (u64*)d_ws;                      // 16384 u64
    u64* bgk = fgk + (size_t)LREF * 256;        // 16384 u64

    k_fused<<<dim3(16, 16, 2), dim3(256), 0, stream>>>(emb, ref, fgk, bgk);
    k_final<<<dim3(LREF), dim3(256), 0, stream>>>(fgk, bgk, out);
}